// Round 1
// baseline (215.214 us; speedup 1.0000x reference)
//
#include <hip/hip_runtime.h>

#define IN_F  64
#define MID_F 128
#define OUT_F 32

typedef __bf16 bf16x8 __attribute__((ext_vector_type(8)));
typedef float  f32x4  __attribute__((ext_vector_type(4)));

// One wave computes 16 rows: x[16x64] -> h[16x128] (ReLU) -> preds[16x32],
// then scatters preds into per-segment sums with fp32 atomics.
// MFMA 16x16x32 bf16. Weights live in registers as B-fragments.
__global__ __launch_bounds__(256) void mlp_scatter_kernel(
    const float* __restrict__ vecs,
    const int*   __restrict__ sidx,
    const float* __restrict__ W1,
    const float* __restrict__ b1,
    const float* __restrict__ W2,
    const float* __restrict__ b2,
    float* __restrict__ osum,
    float* __restrict__ counts,
    int nrows)
{
    // Weights transposed in LDS: [n][k] so B-fragments are contiguous 16B reads.
    __shared__ __align__(16) __bf16 sW1T[MID_F][IN_F];   // 16 KB
    __shared__ __align__(16) __bf16 sW2T[OUT_F][MID_F];  // 8 KB
    __shared__ float sB1[MID_F];
    __shared__ float sB2[OUT_F];
    // Per-wave h staging, bf16, padded 128->136 (stride 272B: 16B-aligned,
    // lane-group rows land on distinct bank octets).
    __shared__ __align__(16) __bf16 sH[4][16][136];      // ~17 KB

    const int tid = threadIdx.x;

    for (int i = tid; i < IN_F * MID_F; i += 256) {
        // W1[k][n], k = i>>7, n = i&127
        sW1T[i & (MID_F - 1)][i >> 7] = (__bf16)W1[i];
    }
    for (int i = tid; i < MID_F * OUT_F; i += 256) {
        // W2[k][n], k = i>>5, n = i&31
        sW2T[i & (OUT_F - 1)][i >> 5] = (__bf16)W2[i];
    }
    if (tid < MID_F) sB1[tid] = b1[tid];
    if (tid < OUT_F) sB2[tid] = b2[tid];
    __syncthreads();

    const int lane = tid & 63;
    const int wid  = tid >> 6;   // wave id 0..3
    const int lg   = lane >> 4;  // k-group 0..3
    const int lr   = lane & 15;  // A-row / B-col / C-col

    // B-fragments in registers, reused for every chunk.
    bf16x8 w1f[8][2];            // [n-tile 0..7][k-tile 0..1]
    #pragma unroll
    for (int t = 0; t < 8; ++t)
        #pragma unroll
        for (int q = 0; q < 2; ++q)
            w1f[t][q] = *(const bf16x8*)&sW1T[t * 16 + lr][q * 32 + lg * 8];
    bf16x8 w2f[2][4];            // [n-tile 0..1][k-tile 0..3]
    #pragma unroll
    for (int t = 0; t < 2; ++t)
        #pragma unroll
        for (int q = 0; q < 4; ++q)
            w2f[t][q] = *(const bf16x8*)&sW2T[t * 16 + lr][q * 32 + lg * 8];

    float bias1[8], bias2[2];
    #pragma unroll
    for (int t = 0; t < 8; ++t) bias1[t] = sB1[t * 16 + lr];
    #pragma unroll
    for (int t = 0; t < 2; ++t) bias2[t] = sB2[t * 16 + lr];

    const int nchunk = nrows >> 4;  // 16 rows per chunk
    for (int c = blockIdx.x * 4 + wid; c < nchunk; c += gridDim.x * 4) {
        const int base = c << 4;

        // ---- Load x tile as two A-fragments (k 0..31, 32..63) ----
        const float* xrow = vecs + (size_t)(base + lr) * IN_F + lg * 8;
        bf16x8 a1[2];
        #pragma unroll
        for (int q = 0; q < 2; ++q) {
            f32x4 u0 = *(const f32x4*)(xrow + q * 32);
            f32x4 u1 = *(const f32x4*)(xrow + q * 32 + 4);
            bf16x8 a;
            #pragma unroll
            for (int j = 0; j < 4; ++j) {
                a[j]     = (__bf16)u0[j];
                a[j + 4] = (__bf16)u1[j];
            }
            a1[q] = a;
        }

        // ---- Layer 1: h = relu(x*W1 + b1), staged to LDS as bf16 ----
        #pragma unroll
        for (int t = 0; t < 8; ++t) {
            f32x4 acc = { bias1[t], bias1[t], bias1[t], bias1[t] };
            acc = __builtin_amdgcn_mfma_f32_16x16x32_bf16(a1[0], w1f[t][0], acc, 0, 0, 0);
            acc = __builtin_amdgcn_mfma_f32_16x16x32_bf16(a1[1], w1f[t][1], acc, 0, 0, 0);
            // C/D layout: col = lane&15, row = (lane>>4)*4 + reg
            #pragma unroll
            for (int r = 0; r < 4; ++r) {
                float v = fmaxf(acc[r], 0.0f);
                sH[wid][lg * 4 + r][t * 16 + lr] = (__bf16)v;
            }
        }
        // DS ops are in-order within a wave; sH[wid] is wave-private.

        // ---- Layer 2: preds = h*W2 + b2 ----
        f32x4 acc2[2];
        acc2[0] = { bias2[0], bias2[0], bias2[0], bias2[0] };
        acc2[1] = { bias2[1], bias2[1], bias2[1], bias2[1] };
        #pragma unroll
        for (int q = 0; q < 4; ++q) {
            bf16x8 a2 = *(const bf16x8*)&sH[wid][lr][q * 32 + lg * 8];
            acc2[0] = __builtin_amdgcn_mfma_f32_16x16x32_bf16(a2, w2f[0][q], acc2[0], 0, 0, 0);
            acc2[1] = __builtin_amdgcn_mfma_f32_16x16x32_bf16(a2, w2f[1][q], acc2[1], 0, 0, 0);
        }

        // ---- Scatter-add into segment sums ----
        int4 sv = *(const int4*)(sidx + base + lg * 4);
        int segs[4] = { sv.x, sv.y, sv.z, sv.w };
        #pragma unroll
        for (int r = 0; r < 4; ++r) {
            float* o = osum + (size_t)segs[r] * OUT_F + lr;
            atomicAdd(o,      acc2[0][r]);   // cols 0..15
            atomicAdd(o + 16, acc2[1][r]);   // cols 16..31
        }
        if (lr == 0) {
            #pragma unroll
            for (int r = 0; r < 4; ++r)
                atomicAdd(counts + segs[r], 1.0f);
        }
    }
}

__global__ __launch_bounds__(256) void finalize_kernel(
    float* __restrict__ osum,
    const float* __restrict__ counts,
    int total)
{
    int i = blockIdx.x * 256 + threadIdx.x;
    if (i < total) {
        float c = counts[i >> 5];   // OUT_F = 32
        osum[i] = osum[i] / fmaxf(c, 1.0f);
    }
}

extern "C" void kernel_launch(void* const* d_in, const int* in_sizes, int n_in,
                              void* d_out, int out_size, void* d_ws, size_t ws_size,
                              hipStream_t stream)
{
    const float* vecs = (const float*)d_in[0];
    const int*   sidx = (const int*)d_in[1];
    // d_in[2] = num_segments scalar on device; derive from out_size instead.
    const float* W1 = (const float*)d_in[3];
    const float* b1 = (const float*)d_in[4];
    const float* W2 = (const float*)d_in[5];
    const float* b2 = (const float*)d_in[6];

    float* osum   = (float*)d_out;
    float* counts = (float*)d_ws;   // nseg floats of scratch

    const int nrows = in_sizes[0] / IN_F;
    const int nseg  = out_size / OUT_F;

    hipMemsetAsync(osum,   0, (size_t)out_size * sizeof(float), stream);
    hipMemsetAsync(counts, 0, (size_t)nseg * sizeof(float), stream);

    mlp_scatter_kernel<<<2048, 256, 0, stream>>>(vecs, sidx, W1, b1, W2, b2,
                                                 osum, counts, nrows);

    finalize_kernel<<<(out_size + 255) / 256, 256, 0, stream>>>(osum, counts, out_size);
}